// Round 1
// baseline (34.992 us; speedup 1.0000x reference)
//
#include <hip/hip_runtime.h>
#include <math.h>

// Ordinal regression loss: mean over (B, K=4) of
//   max(x,0) - x*[k < label] + log1p(exp(-|x|))
// Memory-bound streaming reduction. Two-pass deterministic reduce.

#define KDIM 4
#define BLOCK 256
#define GRID 2048

__global__ __launch_bounds__(BLOCK) void ordloss_partial(
    const float4* __restrict__ logits,   // B rows, one float4 per row (K=4)
    const int* __restrict__ labels,      // B int32
    float* __restrict__ partial,         // GRID floats
    int B)
{
    int tid = blockIdx.x * BLOCK + threadIdx.x;
    const int stride = GRID * BLOCK;

    float acc = 0.0f;
    for (int i = tid; i < B; i += stride) {
        float4 x = logits[i];
        int lab = labels[i];
        float xs[KDIM] = {x.x, x.y, x.z, x.w};
#pragma unroll
        for (int k = 0; k < KDIM; ++k) {
            float v = xs[k];
            float t = (k < lab) ? 1.0f : 0.0f;
            float a = fabsf(v);
            // softplus(-a) = log(1 + exp(-a)), a >= 0 so exp(-a) <= 1 (stable)
            float sp = __logf(1.0f + __expf(-a));
            acc += fmaxf(v, 0.0f) - v * t + sp;
        }
    }

    // wave64 shuffle reduction
#pragma unroll
    for (int off = 32; off > 0; off >>= 1)
        acc += __shfl_down(acc, off, 64);

    __shared__ float wsum[BLOCK / 64];
    int lane = threadIdx.x & 63;
    int wid  = threadIdx.x >> 6;
    if (lane == 0) wsum[wid] = acc;
    __syncthreads();
    if (threadIdx.x == 0) {
        float s = 0.0f;
#pragma unroll
        for (int w = 0; w < BLOCK / 64; ++w) s += wsum[w];
        partial[blockIdx.x] = s;
    }
}

__global__ __launch_bounds__(BLOCK) void ordloss_final(
    const float* __restrict__ partial, int n,
    float* __restrict__ out, float inv_count)
{
    float acc = 0.0f;
    for (int i = threadIdx.x; i < n; i += BLOCK) acc += partial[i];
#pragma unroll
    for (int off = 32; off > 0; off >>= 1)
        acc += __shfl_down(acc, off, 64);

    __shared__ float wsum[BLOCK / 64];
    int lane = threadIdx.x & 63;
    int wid  = threadIdx.x >> 6;
    if (lane == 0) wsum[wid] = acc;
    __syncthreads();
    if (threadIdx.x == 0) {
        float s = 0.0f;
#pragma unroll
        for (int w = 0; w < BLOCK / 64; ++w) s += wsum[w];
        out[0] = s * inv_count;
    }
}

extern "C" void kernel_launch(void* const* d_in, const int* in_sizes, int n_in,
                              void* d_out, int out_size, void* d_ws, size_t ws_size,
                              hipStream_t stream) {
    const float4* logits = (const float4*)d_in[0];
    const int*    labels = (const int*)d_in[1];
    float*        out    = (float*)d_out;
    float*        partial = (float*)d_ws;   // GRID floats = 8 KiB

    int B = in_sizes[1];  // labels count = rows
    float inv_count = 1.0f / ((float)B * (float)KDIM);

    ordloss_partial<<<GRID, BLOCK, 0, stream>>>(logits, labels, partial, B);
    ordloss_final<<<1, BLOCK, 0, stream>>>(partial, GRID, out, inv_count);
}